// Round 6
// baseline (2244.962 us; speedup 1.0000x reference)
//
#include <hip/hip_runtime.h>
#include <math.h>

static constexpr int T_LEN  = 1024;
static constexpr int B_SZ   = 32;
static constexpr int I_SZ   = 1024;
static constexpr int H_SZ   = 256;
static constexpr int M_ROWS = B_SZ * T_LEN;   // 32768 rows = (b,t) flattened

// ---------------------------------------------------------------------------
// Projection GEMM (unchanged, known-good: ~100 TF = 63% of fp32 vector peak):
// C[z, m, n] = sum_k A[m,k] * Bw[z,n,k] + bih[z,n] + bhh[z,n]
// ---------------------------------------------------------------------------
__global__ __launch_bounds__(256, 2)
void proj_gemm(const float* __restrict__ A, int K,
               const float* __restrict__ Bw,
               const float* __restrict__ bih,
               const float* __restrict__ bhh,
               float* __restrict__ C)
{
    __shared__ float As[32][132];   // [k][m], +4 pad words per row
    __shared__ float Bs[32][132];   // [k][n]

    const int tid = threadIdx.x;
    const int m0  = blockIdx.x * 128;
    const int n0  = blockIdx.y * 128;
    const int z   = blockIdx.z;

    const float* Bz = Bw + (size_t)z * H_SZ * K;
    float*       Cz = C  + (size_t)z * M_ROWS * H_SZ;

    const int lr = tid >> 3;        // 0..31
    const int lc = (tid & 7) * 4;   // 0..28

    const int tm = tid & 15;        // m-group (8 rows each)
    const int tn = tid >> 4;        // n-group (8 cols each)

    float acc[8][8];
    #pragma unroll
    for (int i = 0; i < 8; ++i)
        #pragma unroll
        for (int j = 0; j < 8; ++j) acc[i][j] = 0.f;

    for (int k0 = 0; k0 < K; k0 += 32) {
        #pragma unroll
        for (int r = 0; r < 4; ++r) {
            const int row = r * 32 + lr;
            float4 av = *(const float4*)(A  + (size_t)(m0 + row) * K + k0 + lc);
            As[lc + 0][row] = av.x; As[lc + 1][row] = av.y;
            As[lc + 2][row] = av.z; As[lc + 3][row] = av.w;
            float4 bv = *(const float4*)(Bz + (size_t)(n0 + row) * K + k0 + lc);
            Bs[lc + 0][row] = bv.x; Bs[lc + 1][row] = bv.y;
            Bs[lc + 2][row] = bv.z; Bs[lc + 3][row] = bv.w;
        }
        __syncthreads();
        #pragma unroll
        for (int kk = 0; kk < 32; ++kk) {
            float a[8], b[8];
            *(float4*)&a[0] = *(const float4*)&As[kk][tm * 8];
            *(float4*)&a[4] = *(const float4*)&As[kk][tm * 8 + 4];
            *(float4*)&b[0] = *(const float4*)&Bs[kk][tn * 8];
            *(float4*)&b[4] = *(const float4*)&Bs[kk][tn * 8 + 4];
            #pragma unroll
            for (int i = 0; i < 8; ++i)
                #pragma unroll
                for (int j = 0; j < 8; ++j)
                    acc[i][j] = fmaf(a[i], b[j], acc[i][j]);
        }
        __syncthreads();
    }

    float bsum[8];
    #pragma unroll
    for (int j = 0; j < 8; ++j) {
        const int n = n0 + tn * 8 + j;
        bsum[j] = bih[z * H_SZ + n] + bhh[z * H_SZ + n];
    }
    #pragma unroll
    for (int i = 0; i < 8; ++i) {
        const int m = m0 + tm * 8 + i;
        float4 v0, v1;
        v0.x = acc[i][0] + bsum[0]; v0.y = acc[i][1] + bsum[1];
        v0.z = acc[i][2] + bsum[2]; v0.w = acc[i][3] + bsum[3];
        v1.x = acc[i][4] + bsum[4]; v1.y = acc[i][5] + bsum[5];
        v1.z = acc[i][6] + bsum[6]; v1.w = acc[i][7] + bsum[7];
        *(float4*)(Cz + (size_t)m * H_SZ + n0 + tn * 8)     = v0;
        *(float4*)(Cz + (size_t)m * H_SZ + n0 + tn * 8 + 4) = v1;
    }
}

// ---------------------------------------------------------------------------
// DPP butterfly helper: lane i receives value from lane i^1 / i^2 (VALU pipe,
// no LDS). quad_perm[1,0,3,2]=0xB1, quad_perm[2,3,0,1]=0x4E.
// ---------------------------------------------------------------------------
__device__ __forceinline__ float dpp_xor1(float x) {
    return __int_as_float(__builtin_amdgcn_mov_dpp(__float_as_int(x), 0xB1, 0xf, 0xf, true));
}
__device__ __forceinline__ float dpp_xor2(float x) {
    return __int_as_float(__builtin_amdgcn_mov_dpp(__float_as_int(x), 0x4E, 0xf, 0xf, true));
}

// ---------------------------------------------------------------------------
// Recurrent scan. One WG per (direction d, batch b) chain; 64 WGs total.
// h_t = tanh(xp_t + Whh[d] @ h_{t-1}), h_{-1}=0, backward for d=1.
// 512 threads = 128 row-pairs (q) x 4 k-groups (g, 64 k each).
// Thread (q,g): rows {2q,2q+1}, k in [64g,64g+64); W slice = 128 VGPR.
//
// ROUND-5 LESSON (VGPR_Count=84): launch_bounds (512,2) alone does NOT keep
// the W slice resident — the compiler rematerialized the w4 loads every
// step, streaming 256KB/step/WG from L2 (~25 TB/s, near per-XCD ceiling).
// FIX: opaque-value asm on every w4 component after the load. The asm
// "may modify" the value, so rematerialization is illegal -> 128 floats
// stay pinned in VGPRs (~170 total, cap 256 at 2 waves/SIMD).
//
// Reduction over 4 k-groups: xor1+xor2 quad_perm DPP (VALU pipe, no LDS).
// h broadcast via padded LDS: word(k) = k + (k>>6)*4 -> the 4 distinct b128
// addrs/wave-read hit disjoint bank-quads; 16 lanes/addr broadcast.
// Double-buffered h -> ONE barrier per step. Branch-free tanh on all lanes:
// tanh(v) = 1 - 2/(exp(2v)+1)  (exact identity, ~1e-7 abs err).
// ---------------------------------------------------------------------------
__global__ __launch_bounds__(512, 2)
void rnn_scan(const float* __restrict__ xp,   // (2, B, T, H)
              const float* __restrict__ Whh,  // (2, H, H)
              float* __restrict__ out)        // (B, T, 2H)
{
    const int tid = threadIdx.x;
    const int d = blockIdx.x >> 5;
    const int b = blockIdx.x & 31;
    const int g = tid & 3;    // k-group: k in [g*64, g*64+64)
    const int q = tid >> 2;   // row-pair: rows {2q, 2q+1}

    const float* xpc  = xp  + (size_t)(d * B_SZ + b) * T_LEN * H_SZ;
    const float* W    = Whh + (size_t)d * H_SZ * H_SZ;
    float*       outc = out + (size_t)b * T_LEN * (2 * H_SZ) + d * H_SZ;

    // register-resident Whh slice: w4[r][c] = W[2q+r][64g+4c .. +3]
    float4 w4[2][16];
    #pragma unroll
    for (int r = 0; r < 2; ++r) {
        const float* wrow = W + (size_t)(2 * q + r) * H_SZ + g * 64;
        #pragma unroll
        for (int c = 0; c < 16; ++c)
            w4[r][c] = *(const float4*)(wrow + 4 * c);
    }
    // Pin the slice: compiler may not re-load what the asm "modified".
    #pragma unroll
    for (int r = 0; r < 2; ++r)
        #pragma unroll
        for (int c = 0; c < 16; ++c)
            asm volatile("" : "+v"(w4[r][c].x), "+v"(w4[r][c].y),
                              "+v"(w4[r][c].z), "+v"(w4[r][c].w));

    // double-buffered padded h: word(k) = k + (k>>6)*4  (268 used, 272 alloc)
    __shared__ float hbuf[2][272];
    for (int i = tid; i < 2 * 272; i += 512) ((float*)hbuf)[i] = 0.f;

    int t = d ? (T_LEN - 1) : 0;
    const int dt = d ? -1 : 1;

    // xp for rows {2q,2q+1}; 4 lanes per quad read the same address (bcast)
    float2 xpv = *(const float2*)(xpc + (size_t)t * H_SZ + 2 * q);
    __syncthreads();

    int p = 0;
    for (int s = 0; s < T_LEN; ++s) {
        const int tnext = t + dt;
        // branch-free prefetch: clamp index, always load (cndmask not branch)
        const int tpre = (s + 1 < T_LEN) ? tnext : t;
        float2 xpn = *(const float2*)(xpc + (size_t)tpre * H_SZ + 2 * q);

        const float* hb = hbuf[p];
        float a0 = 0.f, a1 = 0.f;
        #pragma unroll
        for (int c = 0; c < 16; ++c) {
            // word(64g+4c) = 68g + 4c  (4c < 64 never crosses a pad block)
            float4 hv = *(const float4*)&hb[68 * g + 4 * c];
            a0 = fmaf(w4[0][c].x, hv.x, a0);
            a0 = fmaf(w4[0][c].y, hv.y, a0);
            a0 = fmaf(w4[0][c].z, hv.z, a0);
            a0 = fmaf(w4[0][c].w, hv.w, a0);
            a1 = fmaf(w4[1][c].x, hv.x, a1);
            a1 = fmaf(w4[1][c].y, hv.y, a1);
            a1 = fmaf(w4[1][c].z, hv.z, a1);
            a1 = fmaf(w4[1][c].w, hv.w, a1);
        }
        // allreduce over the 4 k-groups (lane bits 0,1) — pure DPP
        a0 += dpp_xor1(a0);  a1 += dpp_xor1(a1);
        a0 += dpp_xor2(a0);  a1 += dpp_xor2(a1);

        // branch-free finalize on ALL lanes (redundant x4, no divergence)
        const float v0 = a0 + xpv.x;
        const float v1 = a1 + xpv.y;
        const float h0 = 1.f - 2.f / (__expf(2.f * v0) + 1.f);
        const float h1 = 1.f - 2.f / (__expf(2.f * v1) + 1.f);

        if (g == 0) {
            // word(2q) = 2q + ((q>>5)<<2); 2q,2q+1 always in the same block
            *(float2*)&hbuf[p ^ 1][2 * q + ((q >> 5) << 2)] = make_float2(h0, h1);
            *(float2*)(outc + (size_t)t * (2 * H_SZ) + 2 * q) = make_float2(h0, h1);
        }
        __syncthreads();   // publishes buf p^1; protects buf p until read
        p ^= 1;
        xpv = xpn;
        t = tnext;
    }
}

// ---------------------------------------------------------------------------
extern "C" void kernel_launch(void* const* d_in, const int* in_sizes, int n_in,
                              void* d_out, int out_size, void* d_ws, size_t ws_size,
                              hipStream_t stream)
{
    (void)in_sizes; (void)n_in; (void)out_size; (void)ws_size;

    const float* x    = (const float*)d_in[0];
    const float* Wih0 = (const float*)d_in[1];
    const float* Whh0 = (const float*)d_in[2];
    const float* bih0 = (const float*)d_in[3];
    const float* bhh0 = (const float*)d_in[4];
    const float* Wih1 = (const float*)d_in[5];
    const float* Whh1 = (const float*)d_in[6];
    const float* bih1 = (const float*)d_in[7];
    const float* bhh1 = (const float*)d_in[8];

    float* out = (float*)d_out;        // (B, T, 2H); also holds layer-0 hs
    float* XP  = (float*)d_ws;         // (2, B, T, H) fp32 = 64 MiB, reused

    dim3 ggrid(M_ROWS / 128, 2, 2);

    // layer 0
    proj_gemm<<<ggrid, 256, 0, stream>>>(x, I_SZ, Wih0, bih0, bhh0, XP);
    rnn_scan<<<64, 512, 0, stream>>>(XP, Whh0, out);
    // layer 1 (reads layer-0 hs from d_out, XP buffer reused)
    proj_gemm<<<ggrid, 256, 0, stream>>>(out, 2 * H_SZ, Wih1, bih1, bhh1, XP);
    rnn_scan<<<64, 512, 0, stream>>>(XP, Whh1, out);
}

// Round 7
// 1742.330 us; speedup vs baseline: 1.2885x; 1.2885x over previous
//
#include <hip/hip_runtime.h>
#include <math.h>

static constexpr int T_LEN  = 1024;
static constexpr int B_SZ   = 32;
static constexpr int I_SZ   = 1024;
static constexpr int H_SZ   = 256;
static constexpr int M_ROWS = B_SZ * T_LEN;   // 32768 rows = (b,t) flattened

typedef short s4v  __attribute__((ext_vector_type(4)));
typedef short s8v  __attribute__((ext_vector_type(8)));
typedef float f4v  __attribute__((ext_vector_type(4)));

// f32 -> bf16 (RTN-even), and hi/lo split helpers
__device__ __forceinline__ unsigned short bf_hi(float f) {
    unsigned int x = __float_as_uint(f);
    return (unsigned short)((x + 0x7fffu + ((x >> 16) & 1u)) >> 16);
}
__device__ __forceinline__ void cvt4(const float4 v, s4v& h, s4v& l) {
    unsigned short h0 = bf_hi(v.x), h1 = bf_hi(v.y), h2 = bf_hi(v.z), h3 = bf_hi(v.w);
    float r0 = v.x - __uint_as_float((unsigned)h0 << 16);
    float r1 = v.y - __uint_as_float((unsigned)h1 << 16);
    float r2 = v.z - __uint_as_float((unsigned)h2 << 16);
    float r3 = v.w - __uint_as_float((unsigned)h3 << 16);
    h = (s4v){(short)h0, (short)h1, (short)h2, (short)h3};
    l = (s4v){(short)bf_hi(r0), (short)bf_hi(r1), (short)bf_hi(r2), (short)bf_hi(r3)};
}
// MFMA fragment load: 8 bf16 for one 16x16x32 operand. Lane needs
// [row][4*kg + jj] (jj=0..3) and [row][16 + 4*kg + jj] from a [.][36] tile.
__device__ __forceinline__ s8v frag_ld(const unsigned short* rowbase, int kg) {
    s4v a = *(const s4v*)(rowbase + 4 * kg);
    s4v b = *(const s4v*)(rowbase + 16 + 4 * kg);
    return __builtin_shufflevector(a, b, 0, 1, 2, 3, 4, 5, 6, 7);
}

// ---------------------------------------------------------------------------
// Split-bf16 MFMA projection GEMM:
//   C[z,m,n] = sum_k A[m,k]*Bw[z,n,k] + bih[z,n] + bhh[z,n]
// A = Ah+Al, B = Bh+Bl (bf16 hi + bf16 residual of f32), computed as
// AhBh + AhBl + AlBh via v_mfma_f32_16x16x32_bf16 (AlBl ~2^-16 rel, dropped).
// BM=BN=128, BK=32, 256 threads = 4 waves (2x2), 4x4 16x16 frags per wave.
// Conversion done in-register during staging (no extra HBM/ws traffic).
// Fragment layouts (guide-verified): A/B lane l: m|n = l&15, k = 4*(l>>4)+jj
// (+16 upper half); D: col = l&15, row = 4*(l>>4)+r.
// LDS tiles [128][36] bf16: 72 B row stride (8 B aligned, <=4-way bank alias).
// ---------------------------------------------------------------------------
__global__ __launch_bounds__(256)
void proj_gemm_mfma(const float* __restrict__ A, int K,
                    const float* __restrict__ Bw,
                    const float* __restrict__ bih,
                    const float* __restrict__ bhh,
                    float* __restrict__ C)
{
    __shared__ unsigned short Ah[128 * 36], Al[128 * 36];
    __shared__ unsigned short Bh[128 * 36], Bl[128 * 36];

    const int tid = threadIdx.x;
    const int m0  = blockIdx.x * 128;
    const int n0  = blockIdx.y * 128;
    const int z   = blockIdx.z;

    const float* Bz = Bw + (size_t)z * H_SZ * K;
    float*       Cz = C  + (size_t)z * M_ROWS * H_SZ;

    const int l  = tid & 63, w  = tid >> 6;
    const int wm = w >> 1,   wn = w & 1;
    const int lm = l & 15,   kg = l >> 4;

    const int srow = tid >> 1;          // 0..127
    const int scol = (tid & 1) * 16;    // 0 or 16 (floats)

    f4v acc[4][4];
    #pragma unroll
    for (int i = 0; i < 4; ++i)
        #pragma unroll
        for (int j = 0; j < 4; ++j) acc[i][j] = (f4v){0.f, 0.f, 0.f, 0.f};

    for (int k0 = 0; k0 < K; k0 += 32) {
        const float* Ar = A  + (size_t)(m0 + srow) * K + k0 + scol;
        const float* Br = Bz + (size_t)(n0 + srow) * K + k0 + scol;
        #pragma unroll
        for (int i = 0; i < 4; ++i) {
            const int o = srow * 36 + scol + 4 * i;
            s4v h, lo;
            cvt4(*(const float4*)(Ar + 4 * i), h, lo);
            *(s4v*)&Ah[o] = h;  *(s4v*)&Al[o] = lo;
            cvt4(*(const float4*)(Br + 4 * i), h, lo);
            *(s4v*)&Bh[o] = h;  *(s4v*)&Bl[o] = lo;
        }
        __syncthreads();

        s8v bhf[4], blf[4];
        #pragma unroll
        for (int fn = 0; fn < 4; ++fn) {
            const int rb = (wn * 64 + fn * 16 + lm) * 36;
            bhf[fn] = frag_ld(&Bh[rb], kg);
            blf[fn] = frag_ld(&Bl[rb], kg);
        }
        #pragma unroll
        for (int fm = 0; fm < 4; ++fm) {
            const int ra = (wm * 64 + fm * 16 + lm) * 36;
            const s8v ahf = frag_ld(&Ah[ra], kg);
            const s8v alf = frag_ld(&Al[ra], kg);
            #pragma unroll
            for (int fn = 0; fn < 4; ++fn) {
                acc[fm][fn] = __builtin_amdgcn_mfma_f32_16x16x32_bf16(ahf, bhf[fn], acc[fm][fn], 0, 0, 0);
                acc[fm][fn] = __builtin_amdgcn_mfma_f32_16x16x32_bf16(ahf, blf[fn], acc[fm][fn], 0, 0, 0);
                acc[fm][fn] = __builtin_amdgcn_mfma_f32_16x16x32_bf16(alf, bhf[fn], acc[fm][fn], 0, 0, 0);
            }
        }
        __syncthreads();
    }

    const int nB = n0 + wn * 64;
    float biasv[4];
    #pragma unroll
    for (int fn = 0; fn < 4; ++fn) {
        const int n = nB + fn * 16 + lm;
        biasv[fn] = bih[z * H_SZ + n] + bhh[z * H_SZ + n];
    }
    #pragma unroll
    for (int fm = 0; fm < 4; ++fm) {
        const int mB = m0 + wm * 64 + fm * 16 + 4 * kg;
        #pragma unroll
        for (int r = 0; r < 4; ++r) {
            float* cr = Cz + (size_t)(mB + r) * H_SZ + nB;
            #pragma unroll
            for (int fn = 0; fn < 4; ++fn)
                cr[fn * 16 + lm] = acc[fm][fn][r] + biasv[fn];
        }
    }
}

// ---------------------------------------------------------------------------
// DPP butterfly helpers (VALU pipe, no LDS).
// ---------------------------------------------------------------------------
__device__ __forceinline__ float dpp_xor1(float x) {
    return __int_as_float(__builtin_amdgcn_mov_dpp(__float_as_int(x), 0xB1, 0xf, 0xf, true));
}
__device__ __forceinline__ float dpp_xor2(float x) {
    return __int_as_float(__builtin_amdgcn_mov_dpp(__float_as_int(x), 0x4E, 0xf, 0xf, true));
}

// ---------------------------------------------------------------------------
// Recurrent scan. One WG per (direction d, batch b) chain; 64 WGs total.
// h_t = tanh(xp_t + Whh[d] @ h_{t-1}), h_{-1}=0, backward for d=1.
// 512 threads = 128 row-pairs (q) x 4 k-groups (g, 64 k each); W slice =
// 128 VGPR/thread.
//
// ROUND-5 LESSON (VGPR=84): bare/min-only launch_bounds -> compiler REMATS
// the W loads every step (L2 stream 256KB/step/WG = the 1580cy/step bound).
// ROUND-6 LESSON (VGPR=76, slower): asm pin without a raised budget ->
// regalloc SPILLS W to scratch instead. The budget lever is
// amdgpu_waves_per_eu(2,2): min=max=2 waves/EU -> VGPR budget 256 ->
// ~170 live regs fit, no spill, no remat (pin keeps remat illegal).
// ---------------------------------------------------------------------------
__global__ __launch_bounds__(512)
__attribute__((amdgpu_waves_per_eu(2, 2)))
void rnn_scan(const float* __restrict__ xp,   // (2, B, T, H)
              const float* __restrict__ Whh,  // (2, H, H)
              float* __restrict__ out)        // (B, T, 2H)
{
    const int tid = threadIdx.x;
    const int d = blockIdx.x >> 5;
    const int b = blockIdx.x & 31;
    const int g = tid & 3;    // k-group: k in [g*64, g*64+64)
    const int q = tid >> 2;   // row-pair: rows {2q, 2q+1}

    const float* xpc  = xp  + (size_t)(d * B_SZ + b) * T_LEN * H_SZ;
    const float* W    = Whh + (size_t)d * H_SZ * H_SZ;
    float*       outc = out + (size_t)b * T_LEN * (2 * H_SZ) + d * H_SZ;

    // register-resident Whh slice: w4[r][c] = W[2q+r][64g+4c .. +3]
    float4 w4[2][16];
    #pragma unroll
    for (int r = 0; r < 2; ++r) {
        const float* wrow = W + (size_t)(2 * q + r) * H_SZ + g * 64;
        #pragma unroll
        for (int c = 0; c < 16; ++c)
            w4[r][c] = *(const float4*)(wrow + 4 * c);
    }
    // Pin: compiler may not re-load what the asm "modified".
    #pragma unroll
    for (int r = 0; r < 2; ++r)
        #pragma unroll
        for (int c = 0; c < 16; ++c)
            asm volatile("" : "+v"(w4[r][c].x), "+v"(w4[r][c].y),
                              "+v"(w4[r][c].z), "+v"(w4[r][c].w));

    // double-buffered padded h: word(k) = k + (k>>6)*4  (268 used, 272 alloc)
    __shared__ float hbuf[2][272];
    for (int i = tid; i < 2 * 272; i += 512) ((float*)hbuf)[i] = 0.f;

    int t = d ? (T_LEN - 1) : 0;
    const int dt = d ? -1 : 1;

    float2 xpv = *(const float2*)(xpc + (size_t)t * H_SZ + 2 * q);
    __syncthreads();

    int p = 0;
    for (int s = 0; s < T_LEN; ++s) {
        const int tnext = t + dt;
        const int tpre = (s + 1 < T_LEN) ? tnext : t;
        float2 xpn = *(const float2*)(xpc + (size_t)tpre * H_SZ + 2 * q);

        const float* hb = hbuf[p];
        float a0 = 0.f, a1 = 0.f;
        #pragma unroll
        for (int c = 0; c < 16; ++c) {
            float4 hv = *(const float4*)&hb[68 * g + 4 * c];
            a0 = fmaf(w4[0][c].x, hv.x, a0);
            a0 = fmaf(w4[0][c].y, hv.y, a0);
            a0 = fmaf(w4[0][c].z, hv.z, a0);
            a0 = fmaf(w4[0][c].w, hv.w, a0);
            a1 = fmaf(w4[1][c].x, hv.x, a1);
            a1 = fmaf(w4[1][c].y, hv.y, a1);
            a1 = fmaf(w4[1][c].z, hv.z, a1);
            a1 = fmaf(w4[1][c].w, hv.w, a1);
        }
        // allreduce over the 4 k-groups (lane bits 0,1) — pure DPP
        a0 += dpp_xor1(a0);  a1 += dpp_xor1(a1);
        a0 += dpp_xor2(a0);  a1 += dpp_xor2(a1);

        // branch-free finalize on ALL lanes (redundant x4, no divergence)
        const float v0 = a0 + xpv.x;
        const float v1 = a1 + xpv.y;
        const float h0 = 1.f - 2.f / (__expf(2.f * v0) + 1.f);
        const float h1 = 1.f - 2.f / (__expf(2.f * v1) + 1.f);

        if (g == 0) {
            *(float2*)&hbuf[p ^ 1][2 * q + ((q >> 5) << 2)] = make_float2(h0, h1);
            *(float2*)(outc + (size_t)t * (2 * H_SZ) + 2 * q) = make_float2(h0, h1);
        }
        __syncthreads();   // publishes buf p^1; protects buf p until read
        p ^= 1;
        xpv = xpn;
        t = tnext;
    }
}

// ---------------------------------------------------------------------------
extern "C" void kernel_launch(void* const* d_in, const int* in_sizes, int n_in,
                              void* d_out, int out_size, void* d_ws, size_t ws_size,
                              hipStream_t stream)
{
    (void)in_sizes; (void)n_in; (void)out_size; (void)ws_size;

    const float* x    = (const float*)d_in[0];
    const float* Wih0 = (const float*)d_in[1];
    const float* Whh0 = (const float*)d_in[2];
    const float* bih0 = (const float*)d_in[3];
    const float* bhh0 = (const float*)d_in[4];
    const float* Wih1 = (const float*)d_in[5];
    const float* Whh1 = (const float*)d_in[6];
    const float* bih1 = (const float*)d_in[7];
    const float* bhh1 = (const float*)d_in[8];

    float* out = (float*)d_out;        // (B, T, 2H); also holds layer-0 hs
    float* XP  = (float*)d_ws;         // (2, B, T, H) fp32 = 64 MiB, reused

    dim3 ggrid(M_ROWS / 128, 2, 2);

    // layer 0
    proj_gemm_mfma<<<ggrid, 256, 0, stream>>>(x, I_SZ, Wih0, bih0, bhh0, XP);
    rnn_scan<<<64, 512, 0, stream>>>(XP, Whh0, out);
    // layer 1 (reads layer-0 hs from d_out, XP buffer reused)
    proj_gemm_mfma<<<ggrid, 256, 0, stream>>>(out, 2 * H_SZ, Wih1, bih1, bhh1, XP);
    rnn_scan<<<64, 512, 0, stream>>>(XP, Whh1, out);
}

// Round 10
// 1687.781 us; speedup vs baseline: 1.3301x; 1.0323x over previous
//
#include <hip/hip_runtime.h>
#include <math.h>

static constexpr int T_LEN  = 1024;
static constexpr int B_SZ   = 32;
static constexpr int I_SZ   = 1024;
static constexpr int H_SZ   = 256;
static constexpr int M_ROWS = B_SZ * T_LEN;   // 32768 rows = (b,t) flattened

typedef short s4v  __attribute__((ext_vector_type(4)));
typedef short s8v  __attribute__((ext_vector_type(8)));
typedef float f4v  __attribute__((ext_vector_type(4)));

// f32 -> bf16 (RTN-even), and hi/lo split helpers
__device__ __forceinline__ unsigned short bf_hi(float f) {
    unsigned int x = __float_as_uint(f);
    return (unsigned short)((x + 0x7fffu + ((x >> 16) & 1u)) >> 16);
}
__device__ __forceinline__ void cvt4(const float4 v, s4v& h, s4v& l) {
    unsigned short h0 = bf_hi(v.x), h1 = bf_hi(v.y), h2 = bf_hi(v.z), h3 = bf_hi(v.w);
    float r0 = v.x - __uint_as_float((unsigned)h0 << 16);
    float r1 = v.y - __uint_as_float((unsigned)h1 << 16);
    float r2 = v.z - __uint_as_float((unsigned)h2 << 16);
    float r3 = v.w - __uint_as_float((unsigned)h3 << 16);
    h = (s4v){(short)h0, (short)h1, (short)h2, (short)h3};
    l = (s4v){(short)bf_hi(r0), (short)bf_hi(r1), (short)bf_hi(r2), (short)bf_hi(r3)};
}
// MFMA fragment load: 8 bf16 for one 16x16x32 operand.
__device__ __forceinline__ s8v frag_ld(const unsigned short* rowbase, int kg) {
    s4v a = *(const s4v*)(rowbase + 4 * kg);
    s4v b = *(const s4v*)(rowbase + 16 + 4 * kg);
    return __builtin_shufflevector(a, b, 0, 1, 2, 3, 4, 5, 6, 7);
}

// ---------------------------------------------------------------------------
// Split-bf16 MFMA projection GEMM (unchanged, known-good):
//   C[z,m,n] = sum_k A[m,k]*Bw[z,n,k] + bih[z,n] + bhh[z,n]
// AhBh + AhBl + AlBh via v_mfma_f32_16x16x32_bf16 (AlBl ~2^-16 rel, dropped).
// ---------------------------------------------------------------------------
__global__ __launch_bounds__(256)
void proj_gemm_mfma(const float* __restrict__ A, int K,
                    const float* __restrict__ Bw,
                    const float* __restrict__ bih,
                    const float* __restrict__ bhh,
                    float* __restrict__ C)
{
    __shared__ unsigned short Ah[128 * 36], Al[128 * 36];
    __shared__ unsigned short Bh[128 * 36], Bl[128 * 36];

    const int tid = threadIdx.x;
    const int m0  = blockIdx.x * 128;
    const int n0  = blockIdx.y * 128;
    const int z   = blockIdx.z;

    const float* Bz = Bw + (size_t)z * H_SZ * K;
    float*       Cz = C  + (size_t)z * M_ROWS * H_SZ;

    const int l  = tid & 63, w  = tid >> 6;
    const int wm = w >> 1,   wn = w & 1;
    const int lm = l & 15,   kg = l >> 4;

    const int srow = tid >> 1;          // 0..127
    const int scol = (tid & 1) * 16;    // 0 or 16 (floats)

    f4v acc[4][4];
    #pragma unroll
    for (int i = 0; i < 4; ++i)
        #pragma unroll
        for (int j = 0; j < 4; ++j) acc[i][j] = (f4v){0.f, 0.f, 0.f, 0.f};

    for (int k0 = 0; k0 < K; k0 += 32) {
        const float* Ar = A  + (size_t)(m0 + srow) * K + k0 + scol;
        const float* Br = Bz + (size_t)(n0 + srow) * K + k0 + scol;
        #pragma unroll
        for (int i = 0; i < 4; ++i) {
            const int o = srow * 36 + scol + 4 * i;
            s4v h, lo;
            cvt4(*(const float4*)(Ar + 4 * i), h, lo);
            *(s4v*)&Ah[o] = h;  *(s4v*)&Al[o] = lo;
            cvt4(*(const float4*)(Br + 4 * i), h, lo);
            *(s4v*)&Bh[o] = h;  *(s4v*)&Bl[o] = lo;
        }
        __syncthreads();

        s8v bhf[4], blf[4];
        #pragma unroll
        for (int fn = 0; fn < 4; ++fn) {
            const int rb = (wn * 64 + fn * 16 + lm) * 36;
            bhf[fn] = frag_ld(&Bh[rb], kg);
            blf[fn] = frag_ld(&Bl[rb], kg);
        }
        #pragma unroll
        for (int fm = 0; fm < 4; ++fm) {
            const int ra = (wm * 64 + fm * 16 + lm) * 36;
            const s8v ahf = frag_ld(&Ah[ra], kg);
            const s8v alf = frag_ld(&Al[ra], kg);
            #pragma unroll
            for (int fn = 0; fn < 4; ++fn) {
                acc[fm][fn] = __builtin_amdgcn_mfma_f32_16x16x32_bf16(ahf, bhf[fn], acc[fm][fn], 0, 0, 0);
                acc[fm][fn] = __builtin_amdgcn_mfma_f32_16x16x32_bf16(ahf, blf[fn], acc[fm][fn], 0, 0, 0);
                acc[fm][fn] = __builtin_amdgcn_mfma_f32_16x16x32_bf16(alf, bhf[fn], acc[fm][fn], 0, 0, 0);
            }
        }
        __syncthreads();
    }

    const int nB = n0 + wn * 64;
    float biasv[4];
    #pragma unroll
    for (int fn = 0; fn < 4; ++fn) {
        const int n = nB + fn * 16 + lm;
        biasv[fn] = bih[z * H_SZ + n] + bhh[z * H_SZ + n];
    }
    #pragma unroll
    for (int fm = 0; fm < 4; ++fm) {
        const int mB = m0 + wm * 64 + fm * 16 + 4 * kg;
        #pragma unroll
        for (int r = 0; r < 4; ++r) {
            float* cr = Cz + (size_t)(mB + r) * H_SZ + nB;
            #pragma unroll
            for (int fn = 0; fn < 4; ++fn)
                cr[fn * 16 + lm] = acc[fm][fn][r] + biasv[fn];
        }
    }
}

// ---------------------------------------------------------------------------
// DPP butterfly helpers (VALU pipe, no LDS).
// ---------------------------------------------------------------------------
__device__ __forceinline__ float dpp_xor1(float x) {
    return __int_as_float(__builtin_amdgcn_mov_dpp(__float_as_int(x), 0xB1, 0xf, 0xf, true));
}
__device__ __forceinline__ float dpp_xor2(float x) {
    return __int_as_float(__builtin_amdgcn_mov_dpp(__float_as_int(x), 0x4E, 0xf, 0xf, true));
}

// ---------------------------------------------------------------------------
// Recurrent scan. One WG per (direction d, batch b) chain; 64 WGs total.
// h_t = tanh(xp_t + Whh[d] @ h_{t-1}), h_{-1}=0, backward for d=1.
// 512 threads = 128 row-pairs (q) x 4 k-groups (g, 64 k each); W slice =
// 128 VGPR/thread.
//
// RESIDENCY HISTORY: r5 (launch_bounds(512,2)) -> RA targeted HIGH occupancy
// (min-waves is only a floor), budget 128 < pressure ~168 -> remat'd W loads
// = L2 stream at the per-XCD BW floor (~1120cy/step). r6/r7: asm pin without
// an effective budget raise -> scratch spill (SGPR 112 = scratch descriptor).
// r8: v_fma_f32 cannot source AGPRs on gfx950 (assembler-verified).
// THIS ROUND (no pin -> worst case is benign r5-remat): force the RA target
// to 2 waves/EU via BOTH (a) amdgpu_waves_per_eu(2,2) (min=max) and (b) an
// 80KB LDS pad so LDS itself caps the CU at 1 WG = 2 waves/EU (the backend
// takes min(LDS-occupancy, attr) for the register budget). Budget 256 >=
// pressure ~168 -> no pressure trigger -> no remat, no spill.
//
// Reduction over 4 k-groups: xor1+xor2 quad_perm DPP (VALU pipe, no LDS).
// h broadcast via padded LDS: word(k) = k + (k>>6)*4 -> 4 distinct b128
// addrs/wave-read in disjoint bank-quads. Double-buffered h -> ONE barrier
// per step. Branch-free tanh via 1 - 2/(exp(2v)+1) (exact identity).
// ---------------------------------------------------------------------------
__global__ __attribute__((amdgpu_flat_work_group_size(512, 512),
                          amdgpu_waves_per_eu(2, 2)))
void rnn_scan(const float* __restrict__ xp,   // (2, B, T, H)
              const float* __restrict__ Whh,  // (2, H, H)
              float* __restrict__ out)        // (B, T, 2H)
{
    const int tid = threadIdx.x;
    const int d = blockIdx.x >> 5;
    const int b = blockIdx.x & 31;
    const int g = tid & 3;    // k-group: k in [g*64, g*64+64)
    const int q = tid >> 2;   // row-pair: rows {2q, 2q+1}

    const float* xpc  = xp  + (size_t)(d * B_SZ + b) * T_LEN * H_SZ;
    const float* W    = Whh + (size_t)d * H_SZ * H_SZ;
    float*       outc = out + (size_t)b * T_LEN * (2 * H_SZ) + d * H_SZ;

    // register-resident Whh slice: w4[r][c] = W[2q+r][64g+4c .. +3]
    float4 w4[2][16];
    #pragma unroll
    for (int r = 0; r < 2; ++r) {
        const float* wrow = W + (size_t)(2 * q + r) * H_SZ + g * 64;
        #pragma unroll
        for (int c = 0; c < 16; ++c)
            w4[r][c] = *(const float4*)(wrow + 4 * c);
    }

    // double-buffered padded h + occupancy-capping pad (forces 1 WG/CU).
    __shared__ float hbuf[2][272];
    __shared__ float wpad[20480];    // 80 KB; total LDS ~82.2 KB > 80 KB
    if (xp == (const float*)1) wpad[tid] = 1.f;   // opaque keep-alive
    for (int i = tid; i < 2 * 272; i += 512) ((float*)hbuf)[i] = 0.f;

    int t = d ? (T_LEN - 1) : 0;
    const int dt = d ? -1 : 1;

    float2 xpv = *(const float2*)(xpc + (size_t)t * H_SZ + 2 * q);
    __syncthreads();

    int p = 0;
    for (int s = 0; s < T_LEN; ++s) {
        const int tnext = t + dt;
        const int tpre = (s + 1 < T_LEN) ? tnext : t;
        float2 xpn = *(const float2*)(xpc + (size_t)tpre * H_SZ + 2 * q);

        const float* hb = hbuf[p];
        float a0 = 0.f, a1 = 0.f;
        #pragma unroll
        for (int c = 0; c < 16; ++c) {
            // word(64g + x) = 68g + x for x in [0,64)
            float4 hv = *(const float4*)&hb[68 * g + 4 * c];
            a0 = fmaf(w4[0][c].x, hv.x, a0);
            a0 = fmaf(w4[0][c].y, hv.y, a0);
            a0 = fmaf(w4[0][c].z, hv.z, a0);
            a0 = fmaf(w4[0][c].w, hv.w, a0);
            a1 = fmaf(w4[1][c].x, hv.x, a1);
            a1 = fmaf(w4[1][c].y, hv.y, a1);
            a1 = fmaf(w4[1][c].z, hv.z, a1);
            a1 = fmaf(w4[1][c].w, hv.w, a1);
        }
        // allreduce over the 4 k-groups (lane bits 0,1) — pure DPP
        a0 += dpp_xor1(a0);  a1 += dpp_xor1(a1);
        a0 += dpp_xor2(a0);  a1 += dpp_xor2(a1);

        // branch-free finalize on ALL lanes (redundant x4, no divergence)
        const float v0 = a0 + xpv.x;
        const float v1 = a1 + xpv.y;
        const float h0 = 1.f - 2.f / (__expf(2.f * v0) + 1.f);
        const float h1 = 1.f - 2.f / (__expf(2.f * v1) + 1.f);

        if (g == 0) {
            *(float2*)&hbuf[p ^ 1][2 * q + ((q >> 5) << 2)] = make_float2(h0, h1);
            *(float2*)(outc + (size_t)t * (2 * H_SZ) + 2 * q) = make_float2(h0, h1);
        }
        __syncthreads();   // publishes buf p^1; protects buf p until read
        p ^= 1;
        xpv = xpn;
        t = tnext;
    }
}

// ---------------------------------------------------------------------------
extern "C" void kernel_launch(void* const* d_in, const int* in_sizes, int n_in,
                              void* d_out, int out_size, void* d_ws, size_t ws_size,
                              hipStream_t stream)
{
    (void)in_sizes; (void)n_in; (void)out_size; (void)ws_size;

    const float* x    = (const float*)d_in[0];
    const float* Wih0 = (const float*)d_in[1];
    const float* Whh0 = (const float*)d_in[2];
    const float* bih0 = (const float*)d_in[3];
    const float* bhh0 = (const float*)d_in[4];
    const float* Wih1 = (const float*)d_in[5];
    const float* Whh1 = (const float*)d_in[6];
    const float* bih1 = (const float*)d_in[7];
    const float* bhh1 = (const float*)d_in[8];

    float* out = (float*)d_out;        // (B, T, 2H); also holds layer-0 hs
    float* XP  = (float*)d_ws;         // (2, B, T, H) fp32 = 64 MiB, reused

    dim3 ggrid(M_ROWS / 128, 2, 2);

    // layer 0
    proj_gemm_mfma<<<ggrid, 256, 0, stream>>>(x, I_SZ, Wih0, bih0, bhh0, XP);
    rnn_scan<<<64, 512, 0, stream>>>(XP, Whh0, out);
    // layer 1 (reads layer-0 hs from d_out, XP buffer reused)
    proj_gemm_mfma<<<ggrid, 256, 0, stream>>>(out, 2 * H_SZ, Wih1, bih1, bhh1, XP);
    rnn_scan<<<64, 512, 0, stream>>>(XP, Whh1, out);
}